// Round 5
// baseline (110.949 us; speedup 1.0000x reference)
//
#include <hip/hip_runtime.h>
#include <math.h>

#define BATCH 8
#define DZ    32
#define NWH   48
#define NBOX  (NWH*NWH)          // 2304
#define KMAX  25
#define PIX   (384*384)          // 147456 per (k,b) slab
#define NTHR  576                // fused box+nms: 9 waves, 4 boxes/thread
#define NW9   9

typedef float vfloat4 __attribute__((ext_vector_type(4)));

__device__ __forceinline__ float sigm(float x) { return 1.0f / (1.0f + expf(-x)); }
// fast softplus: max(x,0) + ln(1+e^{-|x|}); abs err ~1e-6
__device__ __forceinline__ float sp_fast(float x) {
    return fmaxf(x, 0.0f) + __logf(1.0f + __expf(-fabsf(x)));
}

// ============ Kernel 1: fused conv1x1 + box decode + greedy NMS ============
// one block per batch; writes pfT[b*32 + k] (prob_few transposed)
__global__ __launch_bounds__(NTHR) void boxnms_kernel(
    const float* __restrict__ z, const float* __restrict__ wz, const float* __restrict__ bz,
    const float* __restrict__ lg, const float* __restrict__ wl, const float* __restrict__ bl,
    float* __restrict__ pfT)
{
    __shared__ vfloat4 boxS[NBOX];                 // 36.9 KB
    __shared__ float   prS[NBOX];                  //  9.2 KB
    __shared__ unsigned long long keyB[2][NW9];    // double-buffered per-wave argmax keys
    __shared__ int idxA[KMAX], okA[KMAX];

    const int b = blockIdx.x, t = threadIdx.x;
    const int iw = t / 12, ihq = t % 12;           // 4 consecutive ih per thread

    // ---- conv1x1 (float4 over ih) ----
    const float* zb = z  + (((size_t)b * DZ) * NWH + iw) * NWH + ihq * 4;
    const float* lb = lg + (((size_t)b * DZ) * NWH + iw) * NWH + ihq * 4;
    float b0 = bz[0], b1 = bz[1], b2 = bz[2], b3 = bz[3], blg = bl[0];
    vfloat4 a0 = {b0,b0,b0,b0}, a1 = {b1,b1,b1,b1}, a2 = {b2,b2,b2,b2},
            a3 = {b3,b3,b3,b3}, al = {blg,blg,blg,blg};
    #pragma unroll 8
    for (int d = 0; d < DZ; ++d) {
        vfloat4 zv = *(const vfloat4*)(zb + (size_t)d * NBOX);
        vfloat4 lv = *(const vfloat4*)(lb + (size_t)d * NBOX);
        float w0 = wz[d], w1 = wz[32+d], w2 = wz[64+d], w3 = wz[96+d], wv = wl[d];
        a0 += zv * w0; a1 += zv * w1; a2 += zv * w2; a3 += zv * w3; al += lv * wv;
    }

    // ---- decode 4 boxes into registers + LDS ----
    float x1r[4], y1r[4], x2r[4], y2r[4], arr[4], mkv[4];
    int   nbs[4];
    {
        float t0v[4] = {a0.x,a0.y,a0.z,a0.w};
        float t1v[4] = {a1.x,a1.y,a1.z,a1.w};
        float t2v[4] = {a2.x,a2.y,a2.z,a2.w};
        float t3v[4] = {a3.x,a3.y,a3.z,a3.w};
        float alv[4] = {al.x,al.y,al.z,al.w};
        #pragma unroll
        for (int c = 0; c < 4; ++c) {
            float tx = sigm(t0v[c]), ty = sigm(t1v[c]), tw = sigm(t2v[c]), th = sigm(t3v[c]);
            float bx = 8.0f * ((float)iw + tx);
            float by = 8.0f * ((float)(ihq*4 + c) + ty);
            float bw = 12.0f + 36.0f * tw;
            float bh = 12.0f + 36.0f * th;
            float x1 = bx - 0.5f*bw, y1 = by - 0.5f*bh, x2 = bx + 0.5f*bw, y2 = by + 0.5f*bh;
            float p  = sigm(alv[c]);
            int   n  = iw * NWH + ihq*4 + c;
            x1r[c]=x1; y1r[c]=y1; x2r[c]=x2; y2r[c]=y2;
            arr[c] = (x2-x1)*(y2-y1);
            mkv[c] = (p > 0.1f) ? p : -INFINITY;
            nbs[c] = n;
            boxS[n] = (vfloat4){x1,y1,x2,y2};
            prS[n]  = p;
        }
    }

    // ---- 25 greedy rounds, ONE barrier each ----
    float sx1=0.f, sy1=0.f, sx2=0.f, sy2=0.f, sar=0.f;
    for (int k = 0; k < KMAX; ++k) {
        unsigned long long best = 0ULL;
        #pragma unroll
        for (int c = 0; c < 4; ++c) {
            if (k > 0 && mkv[c] != -INFINITY) {
                float xi1 = fmaxf(sx1, x1r[c]);
                float yi1 = fmaxf(sy1, y1r[c]);
                float xi2 = fminf(sx2, x2r[c]);
                float yi2 = fminf(sy2, y2r[c]);
                float inter = fmaxf(xi2 - xi1, 0.f) * fmaxf(yi2 - yi1, 0.f);
                float uni   = sar + arr[c] - inter;
                float iou   = inter / fmaxf(uni, 1e-8f);
                if (iou > 0.3f) mkv[c] = -INFINITY;
            }
            if (mkv[c] != -INFINITY) {
                unsigned long long kk =
                    ((unsigned long long)__float_as_uint(mkv[c]) << 32) | (unsigned int)(~nbs[c]);
                if (kk > best) best = kk;
            }
        }
        #pragma unroll
        for (int off = 32; off > 0; off >>= 1) {
            unsigned long long o = __shfl_down(best, off);
            if (o > best) best = o;
        }
        if ((t & 63) == 0) keyB[k & 1][t >> 6] = best;
        __syncthreads();
        unsigned long long m = keyB[k & 1][0];
        #pragma unroll
        for (int w = 1; w < NW9; ++w) {
            unsigned long long o = keyB[k & 1][w];
            if (o > m) m = o;
        }
        int sel = (m == 0ULL) ? 0 : (int)(~(unsigned int)(m & 0xFFFFFFFFULL));
        if (t == 0) { idxA[k] = sel; okA[k] = (m != 0ULL); }
        vfloat4 sb = boxS[sel];
        sx1 = sb.x; sy1 = sb.y; sx2 = sb.z; sy2 = sb.w;
        sar = (sx2 - sx1) * (sy2 - sy1);
    }

    if (t == 0) {
        #pragma unroll 1
        for (int k = 0; k < KMAX; ++k) {
            float mm = 0.f;
            for (int k2 = 0; k2 < KMAX; ++k2)
                if (idxA[k2] == idxA[k] && okA[k2]) mm = 1.f;
            pfT[b * 32 + k] = prS[idxA[k]] * mm;
        }
    }
}

// ============ Kernel 2: big streaming op (recompute, no per-k state) ============
// out[k,b,p] = pfT[b,k] * tanh(S)/max(S,1e-6) * softplus(wl[k,b,p]); S = sum_k softplus
// Loop 1 accumulates S only; loop 2 re-reads the (now L2/L3-resident) slabs and
// recomputes softplus. Round-4 lesson: storing sp[25] in regs -> VGPR 120,
// 17% occupancy, latency-bound. Recompute keeps live state ~12 regs.
__global__ __launch_bounds__(256) void big_kernel(const float* __restrict__ wlg,
                                                  const float* __restrict__ pfT,
                                                  float* __restrict__ out)
{
    const size_t stride = (size_t)BATCH * PIX;
    const int b = (int)(((size_t)blockIdx.x * 1024) / PIX);   // block-uniform batch idx
    const size_t j = ((size_t)blockIdx.x * 256 + threadIdx.x) * 4;
    const float* base = wlg + j;

    float sx = 0.f, sy = 0.f, sz = 0.f, sw = 0.f;
    #pragma unroll 5
    for (int k = 0; k < KMAX; ++k) {
        vfloat4 v = *(const vfloat4*)(base + (size_t)k * stride);
        sx += sp_fast(v.x); sy += sp_fast(v.y); sz += sp_fast(v.z); sw += sp_fast(v.w);
    }
    // m = tanh(S)/max(S,1e-6); S>0:  tanh(S) = (1-e^{-2S})/(1+e^{-2S})
    float mx, my, mz, mw;
    {
        float ex = __expf(-2.f*sx), ey = __expf(-2.f*sy), ez = __expf(-2.f*sz), ew = __expf(-2.f*sw);
        mx = (1.f - ex) * __builtin_amdgcn_rcpf(1.f + ex) * __builtin_amdgcn_rcpf(fmaxf(sx, 1e-6f));
        my = (1.f - ey) * __builtin_amdgcn_rcpf(1.f + ey) * __builtin_amdgcn_rcpf(fmaxf(sy, 1e-6f));
        mz = (1.f - ez) * __builtin_amdgcn_rcpf(1.f + ez) * __builtin_amdgcn_rcpf(fmaxf(sz, 1e-6f));
        mw = (1.f - ew) * __builtin_amdgcn_rcpf(1.f + ew) * __builtin_amdgcn_rcpf(fmaxf(sw, 1e-6f));
    }
    #pragma unroll 5
    for (int k = 0; k < KMAX; ++k) {
        vfloat4 v = *(const vfloat4*)(base + (size_t)k * stride);
        float c = pfT[b * 32 + k];                 // uniform -> scalar load
        vfloat4 o = { c * mx * sp_fast(v.x), c * my * sp_fast(v.y),
                      c * mz * sp_fast(v.z), c * mw * sp_fast(v.w) };
        __builtin_nontemporal_store(o, (vfloat4*)(out + (size_t)k * stride + j));
    }
}

extern "C" void kernel_launch(void* const* d_in, const int* in_sizes, int n_in,
                              void* d_out, int out_size, void* d_ws, size_t ws_size,
                              hipStream_t stream)
{
    const float* zwhere = (const float*)d_in[0];
    const float* w_zw   = (const float*)d_in[1];
    const float* b_zw   = (const float*)d_in[2];
    const float* logit  = (const float*)d_in[3];
    const float* w_lg   = (const float*)d_in[4];
    const float* b_lg   = (const float*)d_in[5];
    const float* wlogit = (const float*)d_in[6];
    float* out = (float*)d_out;
    float* pfT = (float*)d_ws;                    // [BATCH][32] prob_few (transposed, padded)

    boxnms_kernel<<<BATCH, NTHR, 0, stream>>>(zwhere, w_zw, b_zw, logit, w_lg, b_lg, pfT);
    const int n4 = BATCH * PIX / 4;               // 294912 threads -> 1152 blocks
    big_kernel<<<n4 / 256, 256, 0, stream>>>(wlogit, pfT, out);
}

// Round 6
// 94.279 us; speedup vs baseline: 1.1768x; 1.1768x over previous
//
#include <hip/hip_runtime.h>
#include <math.h>

#define BATCH 8
#define DZ    32
#define NWH   48
#define NBOX  (NWH*NWH)          // 2304
#define KMAX  25
#define PIX   (384*384)          // 147456 per (k,b) slab
#define NTHR  576                // fused box+nms: 9 waves, 4 boxes/thread
#define NW9   9

typedef float vfloat4 __attribute__((ext_vector_type(4)));

__device__ __forceinline__ float sigm(float x) { return 1.0f / (1.0f + expf(-x)); }
// fast softplus: max(x,0) + ln(1+e^{-|x|}); abs err ~1e-6
__device__ __forceinline__ float sp_fast(float x) {
    return fmaxf(x, 0.0f) + __logf(1.0f + __expf(-fabsf(x)));
}

// ============ Kernel 1: fused conv1x1 + box decode + greedy NMS ============
// one block per batch; writes pfT[b*32 + k] (prob_few transposed)
__global__ __launch_bounds__(NTHR) void boxnms_kernel(
    const float* __restrict__ z, const float* __restrict__ wz, const float* __restrict__ bz,
    const float* __restrict__ lg, const float* __restrict__ wl, const float* __restrict__ bl,
    float* __restrict__ pfT)
{
    __shared__ vfloat4 boxS[NBOX];                 // 36.9 KB
    __shared__ float   prS[NBOX];                  //  9.2 KB
    __shared__ unsigned long long keyB[2][NW9];    // double-buffered per-wave argmax keys
    __shared__ int idxA[KMAX], okA[KMAX];

    const int b = blockIdx.x, t = threadIdx.x;
    const int iw = t / 12, ihq = t % 12;           // 4 consecutive ih per thread

    // ---- conv1x1 (float4 over ih) ----
    const float* zb = z  + (((size_t)b * DZ) * NWH + iw) * NWH + ihq * 4;
    const float* lb = lg + (((size_t)b * DZ) * NWH + iw) * NWH + ihq * 4;
    float b0 = bz[0], b1 = bz[1], b2 = bz[2], b3 = bz[3], blg = bl[0];
    vfloat4 a0 = {b0,b0,b0,b0}, a1 = {b1,b1,b1,b1}, a2 = {b2,b2,b2,b2},
            a3 = {b3,b3,b3,b3}, al = {blg,blg,blg,blg};
    #pragma unroll 8
    for (int d = 0; d < DZ; ++d) {
        vfloat4 zv = *(const vfloat4*)(zb + (size_t)d * NBOX);
        vfloat4 lv = *(const vfloat4*)(lb + (size_t)d * NBOX);
        float w0 = wz[d], w1 = wz[32+d], w2 = wz[64+d], w3 = wz[96+d], wv = wl[d];
        a0 += zv * w0; a1 += zv * w1; a2 += zv * w2; a3 += zv * w3; al += lv * wv;
    }

    // ---- decode 4 boxes into registers + LDS ----
    float x1r[4], y1r[4], x2r[4], y2r[4], arr[4], mkv[4];
    int   nbs[4];
    {
        float t0v[4] = {a0.x,a0.y,a0.z,a0.w};
        float t1v[4] = {a1.x,a1.y,a1.z,a1.w};
        float t2v[4] = {a2.x,a2.y,a2.z,a2.w};
        float t3v[4] = {a3.x,a3.y,a3.z,a3.w};
        float alv[4] = {al.x,al.y,al.z,al.w};
        #pragma unroll
        for (int c = 0; c < 4; ++c) {
            float tx = sigm(t0v[c]), ty = sigm(t1v[c]), tw = sigm(t2v[c]), th = sigm(t3v[c]);
            float bx = 8.0f * ((float)iw + tx);
            float by = 8.0f * ((float)(ihq*4 + c) + ty);
            float bw = 12.0f + 36.0f * tw;
            float bh = 12.0f + 36.0f * th;
            float x1 = bx - 0.5f*bw, y1 = by - 0.5f*bh, x2 = bx + 0.5f*bw, y2 = by + 0.5f*bh;
            float p  = sigm(alv[c]);
            int   n  = iw * NWH + ihq*4 + c;
            x1r[c]=x1; y1r[c]=y1; x2r[c]=x2; y2r[c]=y2;
            arr[c] = (x2-x1)*(y2-y1);
            mkv[c] = (p > 0.1f) ? p : -INFINITY;
            nbs[c] = n;
            boxS[n] = (vfloat4){x1,y1,x2,y2};
            prS[n]  = p;
        }
    }

    // ---- 25 greedy rounds, ONE barrier each ----
    float sx1=0.f, sy1=0.f, sx2=0.f, sy2=0.f, sar=0.f;
    for (int k = 0; k < KMAX; ++k) {
        unsigned long long best = 0ULL;
        #pragma unroll
        for (int c = 0; c < 4; ++c) {
            if (k > 0 && mkv[c] != -INFINITY) {
                float xi1 = fmaxf(sx1, x1r[c]);
                float yi1 = fmaxf(sy1, y1r[c]);
                float xi2 = fminf(sx2, x2r[c]);
                float yi2 = fminf(sy2, y2r[c]);
                float inter = fmaxf(xi2 - xi1, 0.f) * fmaxf(yi2 - yi1, 0.f);
                float uni   = sar + arr[c] - inter;
                float iou   = inter / fmaxf(uni, 1e-8f);
                if (iou > 0.3f) mkv[c] = -INFINITY;
            }
            if (mkv[c] != -INFINITY) {
                unsigned long long kk =
                    ((unsigned long long)__float_as_uint(mkv[c]) << 32) | (unsigned int)(~nbs[c]);
                if (kk > best) best = kk;
            }
        }
        #pragma unroll
        for (int off = 32; off > 0; off >>= 1) {
            unsigned long long o = __shfl_down(best, off);
            if (o > best) best = o;
        }
        if ((t & 63) == 0) keyB[k & 1][t >> 6] = best;
        __syncthreads();
        unsigned long long m = keyB[k & 1][0];
        #pragma unroll
        for (int w = 1; w < NW9; ++w) {
            unsigned long long o = keyB[k & 1][w];
            if (o > m) m = o;
        }
        int sel = (m == 0ULL) ? 0 : (int)(~(unsigned int)(m & 0xFFFFFFFFULL));
        if (t == 0) { idxA[k] = sel; okA[k] = (m != 0ULL); }
        vfloat4 sb = boxS[sel];
        sx1 = sb.x; sy1 = sb.y; sx2 = sb.z; sy2 = sb.w;
        sar = (sx2 - sx1) * (sy2 - sy1);
    }

    if (t == 0) {
        #pragma unroll 1
        for (int k = 0; k < KMAX; ++k) {
            float mm = 0.f;
            for (int k2 = 0; k2 < KMAX; ++k2)
                if (idxA[k2] == idxA[k] && okA[k2]) mm = 1.f;
            pfT[b * 32 + k] = prS[idxA[k]] * mm;
        }
    }
}

// ============ Kernel 2: big streaming op — k split across 4-lane groups ============
// lane r = t&3 owns slabs {6r..6r+5} (+ slab 24 on r==0); lanes sharing t>>2 share
// the same 4-px column j. One pass; state = 6-7 vfloat4 sp regs; S combined by
// 4-lane shfl_xor butterfly. 4x the waves of the old layout (18432 total).
__global__ __launch_bounds__(256) void big_kernel(const float* __restrict__ wlg,
                                                  const float* __restrict__ pfT,
                                                  float* __restrict__ out)
{
    const size_t stride = (size_t)BATCH * PIX;
    const int t = threadIdx.x;
    const int r = t & 3;
    const size_t j = ((size_t)blockIdx.x * 64 + (t >> 2)) * 4;   // 4-px column
    const int b = (int)(blockIdx.x / 576);                       // block-uniform
    const int kb = 6 * r;
    const float* base = wlg + (size_t)kb * stride + j;

    vfloat4 acc = {0.f, 0.f, 0.f, 0.f};
    vfloat4 sp0, sp1, sp2, sp3, sp4, sp5;
#define LOADSP(s) { vfloat4 v = *(const vfloat4*)(base + (size_t)(s) * stride); \
    sp##s = (vfloat4){ sp_fast(v.x), sp_fast(v.y), sp_fast(v.z), sp_fast(v.w) }; \
    acc += sp##s; }
    LOADSP(0) LOADSP(1) LOADSP(2) LOADSP(3) LOADSP(4) LOADSP(5)
#undef LOADSP
    vfloat4 sp6 = {0.f, 0.f, 0.f, 0.f};
    if (r == 0) {
        vfloat4 v = *(const vfloat4*)(wlg + (size_t)24 * stride + j);
        sp6 = (vfloat4){ sp_fast(v.x), sp_fast(v.y), sp_fast(v.z), sp_fast(v.w) };
        acc += sp6;
    }

    // 4-lane butterfly: lanes {4q..4q+3} sum their partial S
    #pragma unroll
    for (int mlane = 1; mlane <= 2; mlane <<= 1) {
        acc.x += __shfl_xor(acc.x, mlane);
        acc.y += __shfl_xor(acc.y, mlane);
        acc.z += __shfl_xor(acc.z, mlane);
        acc.w += __shfl_xor(acc.w, mlane);
    }

    // m = tanh(S)/max(S,1e-6); S>=0:  tanh(S) = (1-e^{-2S})/(1+e^{-2S})
    vfloat4 m;
    {
        float ex = __expf(-2.f*acc.x), ey = __expf(-2.f*acc.y),
              ez = __expf(-2.f*acc.z), ew = __expf(-2.f*acc.w);
        m.x = (1.f - ex) * __builtin_amdgcn_rcpf(1.f + ex) * __builtin_amdgcn_rcpf(fmaxf(acc.x, 1e-6f));
        m.y = (1.f - ey) * __builtin_amdgcn_rcpf(1.f + ey) * __builtin_amdgcn_rcpf(fmaxf(acc.y, 1e-6f));
        m.z = (1.f - ez) * __builtin_amdgcn_rcpf(1.f + ez) * __builtin_amdgcn_rcpf(fmaxf(acc.z, 1e-6f));
        m.w = (1.f - ew) * __builtin_amdgcn_rcpf(1.f + ew) * __builtin_amdgcn_rcpf(fmaxf(acc.w, 1e-6f));
    }

    const float* pfb = pfT + b * 32 + kb;
    float* ob = out + (size_t)kb * stride + j;
#define STORE(s) { float c = pfb[s]; \
    vfloat4 o = { c * m.x * sp##s.x, c * m.y * sp##s.y, c * m.z * sp##s.z, c * m.w * sp##s.w }; \
    __builtin_nontemporal_store(o, (vfloat4*)(ob + (size_t)(s) * stride)); }
    STORE(0) STORE(1) STORE(2) STORE(3) STORE(4) STORE(5)
#undef STORE
    if (r == 0) {
        float c = pfT[b * 32 + 24];
        vfloat4 o = { c * m.x * sp6.x, c * m.y * sp6.y, c * m.z * sp6.z, c * m.w * sp6.w };
        __builtin_nontemporal_store(o, (vfloat4*)(out + (size_t)24 * stride + j));
    }
}

extern "C" void kernel_launch(void* const* d_in, const int* in_sizes, int n_in,
                              void* d_out, int out_size, void* d_ws, size_t ws_size,
                              hipStream_t stream)
{
    const float* zwhere = (const float*)d_in[0];
    const float* w_zw   = (const float*)d_in[1];
    const float* b_zw   = (const float*)d_in[2];
    const float* logit  = (const float*)d_in[3];
    const float* w_lg   = (const float*)d_in[4];
    const float* b_lg   = (const float*)d_in[5];
    const float* wlogit = (const float*)d_in[6];
    float* out = (float*)d_out;
    float* pfT = (float*)d_ws;                    // [BATCH][32] prob_few (transposed, padded)

    boxnms_kernel<<<BATCH, NTHR, 0, stream>>>(zwhere, w_zw, b_zw, logit, w_lg, b_lg, pfT);
    // 4608 blocks: each covers 64 four-px columns x all 25 slabs (k split over lanes)
    big_kernel<<<(BATCH * PIX) / 256, 256, 0, stream>>>(wlogit, pfT, out);
}